// Round 4
// baseline (870.779 us; speedup 1.0000x reference)
//
#include <hip/hip_runtime.h>
#include <math.h>

// SLAYER SNN forward, 6 layers, T=2048.
// Double-precision "true value" policy: outputs are binary spikes matching the
// golden fp32 reference; double noise (~1e-13) << reference fp32 noise (~1e-5),
// so any double summation order/reassociation is safe.
//
// PSP (100-tap truncated SRM FIR) folded into an exact 2nd-order IIR:
//   h[k] = c*k*b^k, b=e^-0.1, c=0.1*e  =>
//   p[t] = 2b p[t-1] - b^2 p[t-2] + cb x[t-1] - 100cb^100 x[t-100] + 99cb^101 x[t-101]
// Fused with the threshold+refractory scan (k_psp_scan). Refractory identity:
//   e1' = a(e1+s), e2' = a(e2+e1+s), a=e^-1;  u' = p' - 2((e1+e2)+s).
// Negative-t input rows come from zeroed pads below each arena.

#define T_BINS 2048
#define K_SRM  100
#define AEXP   0.36787944117144233   // e^-1
#define PF     16                    // psp_scan prefetch depth
#define SPF    32                    // scan1 prefetch depth (unused now)

// ---------------- init: Scum prefix table for layer-1 scan ------------------
__global__ __launch_bounds__(64) void k_init(double* __restrict__ Scum) {
  if (threadIdx.x == 0) {
    double acc = 0.0;
    for (int t = 0; t < K_SRM; ++t) {
      double tk = (double)t;
      acc += (tk * 0.1) * exp(1.0 - tk * 0.1);
      Scum[t] = acc;
    }
  }
}

// ---------------- conv1: [3,32,32] x [6,3,5,5] -> c1[4704] ------------------
__global__ __launch_bounds__(256) void k_conv1(const float* __restrict__ x,
                                               const float* __restrict__ W,
                                               float* __restrict__ c1) {
  int idx = blockIdx.x * blockDim.x + threadIdx.x;
  if (idx >= 4704) return;
  int o = idx / 784, r = idx % 784, i = r / 28, j = r % 28;
  double acc = 0.0;
  for (int ci = 0; ci < 3; ++ci)
    for (int ky = 0; ky < 5; ++ky) {
      const float* xr = x + ci * 1024 + (i + ky) * 32 + j;
      const float* wr = W + ((o * 3 + ci) * 5 + ky) * 5;
#pragma unroll
      for (int kx = 0; kx < 5; ++kx)
        acc += (double)xr[kx] * (double)wr[kx];
    }
  c1[idx] = (float)acc;
}

// ---------------- layer1 spike scan: p1[t] = c1*Scum[t] ---------------------
__global__ __launch_bounds__(256) void k_scan1(const float* __restrict__ c1,
                                               const double* __restrict__ Scum_g,
                                               unsigned char* __restrict__ s1b) {
  __shared__ double Sc[K_SRM];
  for (int k = threadIdx.x; k < K_SRM; k += blockDim.x) Sc[k] = Scum_g[k];
  __syncthreads();
  int n = blockIdx.x * blockDim.x + threadIdx.x;
  if (n >= 4704) return;
  double w = (double)c1[n];
  double e1 = 0.0, e2 = 0.0;
  double u = 0.0;                       // w*Scum[0] == 0
  unsigned char* outp = s1b + n;
  int t = 0;
#pragma unroll 4
  for (; t < K_SRM - 1; ++t) {          // ramp phase, uses Sc[t+1]
    double s = (u >= 1.0) ? 1.0 : 0.0;
    outp[(size_t)t * 4704] = (unsigned char)s;
    u = w * Sc[t + 1] - 2.0 * ((e1 + e2) + s);
    double t1 = e1 + s;
    e2 = AEXP * (e2 + t1);
    e1 = AEXP * t1;
  }
  double wS = w * Sc[K_SRM - 1];        // steady-state drive
#pragma unroll 8
  for (; t < T_BINS; ++t) {
    double s = (u >= 1.0) ? 1.0 : 0.0;
    outp[(size_t)t * 4704] = (unsigned char)s;
    u = wS - 2.0 * ((e1 + e2) + s);
    double t1 = e1 + s;
    e2 = AEXP * (e2 + t1);
    e1 = AEXP * t1;
  }
}

// ---------------- pool: 2x2 spike count -> y2b[t][1176] bytes ---------------
__global__ __launch_bounds__(256) void k_pool(const unsigned char* __restrict__ s1b,
                                              unsigned char* __restrict__ y2b) {
  int idx = blockIdx.x * blockDim.x + threadIdx.x;
  if (idx >= 1176 * T_BINS) return;
  int t = idx / 1176, n2 = idx - t * 1176;
  int c = n2 / 196, r = n2 % 196, i = r / 14, j = r % 14;
  const unsigned char* b = s1b + (size_t)t * 4704 + c * 784 + (2 * i) * 28 + 2 * j;
  y2b[idx] = (unsigned char)((int)b[0] + (int)b[1] + (int)b[28] + (int)b[29]);
}

// ---------------- fused PSP(IIR) + spike scan -------------------------------
// Input rows t-1..: streams x[t] (cur) and x[t-99] (lag); x[t-100] is a delay
// register. Rows <0 read the zeroed pad below z; prefetch overshoot past row
// 2047 lands in in-bounds slack (values unused).
template <typename Tin, typename Tout>
__global__ __launch_bounds__(256) void k_psp_scan(
    const Tin* __restrict__ z, Tout* __restrict__ sout, int N,
    long strideT, long strideN,
    double A1, double A2, double B1, double C0, double C1) {
  int n = blockIdx.x * blockDim.x + threadIdx.x;
  if (n >= N) return;
  const Tin* zn = z + n;
  double pp1 = 0.0, pp2 = 0.0, u = 0.0, e1 = 0.0, e2 = 0.0, xm100 = 0.0;
  float cA[PF], cB[PF], lA[PF], lB[PF];
  size_t oa = (size_t)n * (size_t)strideN;
#define PREFX(BUF, TB)                                               \
  { long tb_ = (long)(TB);                                           \
    _Pragma("unroll")                                                \
    for (int j_ = 0; j_ < PF; ++j_)                                  \
      BUF[j_] = (float)zn[(tb_ + j_) * (long)N]; }
#define GRPX(CUR, LAG)                                               \
  { _Pragma("unroll")                                                \
    for (int j_ = 0; j_ < PF; ++j_) {                                \
      double s = (u >= 1.0) ? 1.0 : 0.0;                             \
      sout[oa] = (Tout)s; oa += (size_t)strideT;                     \
      double xt = (double)CUR[j_], x99 = (double)LAG[j_];            \
      double pn = A1 * pp1 - A2 * pp2 + B1 * xt - C0 * x99           \
                  + C1 * xm100;                                      \
      xm100 = x99;                                                   \
      u = pn - 2.0 * ((e1 + e2) + s);                                \
      double t1 = e1 + s;                                            \
      e2 = AEXP * (e2 + t1);                                         \
      e1 = AEXP * t1;                                                \
      pp2 = pp1; pp1 = pn;                                           \
    } }
  PREFX(cA, 0)
  PREFX(lA, -99)
  for (int g = 0; g < T_BINS / PF; g += 2) {
    PREFX(cB, (g + 1) * PF)
    PREFX(lB, (g + 1) * PF - 99)
    GRPX(cA, lA)
    PREFX(cA, (g + 2) * PF)        // last iter overshoots into slack (unused)
    PREFX(lA, (g + 2) * PF - 99)
    GRPX(cB, lB)
  }
#undef PREFX
#undef GRPX
}

// ---------------- conv2: per-t [6,14,14] x [16,6,5,5] -> z3[t][1600] --------
__global__ __launch_bounds__(256) void k_conv2(const unsigned char* __restrict__ s2b,
                                               const float* __restrict__ W,
                                               float* __restrict__ z3) {
  __shared__ float ls[1176];
  __shared__ float lw[2400];
  int t = blockIdx.x;
  for (int i = threadIdx.x; i < 1176; i += 256)
    ls[i] = (float)s2b[(size_t)t * 1176 + i];
  for (int i = threadIdx.x; i < 2400; i += 256) lw[i] = W[i];
  __syncthreads();
  for (int rr = threadIdx.x; rr < 1600; rr += 256) {
    int o = rr / 100, ij = rr % 100, i = ij / 10, j = ij % 10;
    double acc = 0.0;
    for (int ci = 0; ci < 6; ++ci)
      for (int ky = 0; ky < 5; ++ky) {
        int sb = ci * 196 + (i + ky) * 14 + j;
        int wb = ((o * 6 + ci) * 5 + ky) * 5;
#pragma unroll
        for (int kx = 0; kx < 5; ++kx)
          acc += (double)ls[sb + kx] * (double)lw[wb + kx];
      }
    z3[(size_t)t * 1600 + rr] = (float)acc;
  }
}

// ---------------- weight transpose: WT[c][o] = W[o][c] ----------------------
__global__ __launch_bounds__(256) void k_transpose(const float* __restrict__ W,
                                                   float* __restrict__ WT,
                                                   int Nout, int Nin) {
  int idx = blockIdx.x * blockDim.x + threadIdx.x;
  if (idx >= Nout * Nin) return;
  int c = idx / Nout, o = idx - c * Nout;   // write-coalesced
  WT[idx] = W[o * Nin + c];
}

// ---------------- sparse dense: z[t][o] = sum_{c active} WT[c][o] -----------
// One block per t. Order-preserving compaction (ascending c), then
// 4-accumulator double sum; list read via int4 LDS broadcast.
template <int NIN, int NOUT, int BLK>
__global__ __launch_bounds__(BLK) void k_dense_sparse(
    const unsigned char* __restrict__ s, const float* __restrict__ WT,
    float* __restrict__ z) {
  constexpr int NCH = (NIN + BLK - 1) / BLK;
  constexpr int NW = BLK / 64;
  __shared__ __align__(16) int list[NIN];
  __shared__ int wcnt[NCH][NW];
  int t = blockIdx.x;
  const unsigned char* srow = s + (size_t)t * NIN;
  int tid = threadIdx.x, lane = tid & 63, wv = tid >> 6;
  unsigned long long msave[NCH];
  bool asave[NCH];
#pragma unroll
  for (int ci = 0; ci < NCH; ++ci) {
    int c = ci * BLK + tid;
    bool a = (c < NIN) && (srow[c] != 0);
    unsigned long long m = __ballot(a);
    msave[ci] = m; asave[ci] = a;
    if (lane == 0) wcnt[ci][wv] = __popcll(m);
  }
  __syncthreads();
  int nact = 0;
#pragma unroll
  for (int ci = 0; ci < NCH; ++ci) {
    int off = nact;
    for (int w = 0; w < wv; ++w) off += wcnt[ci][w];
    if (asave[ci])
      list[off + __popcll(msave[ci] & ((1ULL << lane) - 1))] = ci * BLK + tid;
    for (int w = 0; w < NW; ++w) nact += wcnt[ci][w];
  }
  __syncthreads();
  if (tid >= NOUT) return;
  const float* col = WT + tid;
  double a0 = 0.0, a1 = 0.0, a2 = 0.0, a3 = 0.0;
  int k = 0, nact4 = nact & ~3;
  for (; k < nact4; k += 4) {
    int4 l4 = *(const int4*)&list[k];
    a0 += (double)col[(size_t)l4.x * NOUT];
    a1 += (double)col[(size_t)l4.y * NOUT];
    a2 += (double)col[(size_t)l4.z * NOUT];
    a3 += (double)col[(size_t)l4.w * NOUT];
  }
  for (; k < nact; ++k) a0 += (double)col[(size_t)list[k] * NOUT];
  z[(size_t)t * NOUT + tid] = (float)((a0 + a1) + (a2 + a3));
}

// ---------------- launch ----------------------------------------------------
extern "C" void kernel_launch(void* const* d_in, const int* in_sizes, int n_in,
                              void* d_out, int out_size, void* d_ws, size_t ws_size,
                              hipStream_t stream) {
  const float* x   = (const float*)d_in[0];
  const float* Wc1 = (const float*)d_in[1];
  const float* Wc2 = (const float*)d_in[2];
  const float* Wf1 = (const float*)d_in[3];
  const float* Wf2 = (const float*)d_in[4];
  const float* Wf3 = (const float*)d_in[5];
  float* out = (float*)d_out;
  char* ws = (char*)d_ws;

  // Workspace layout (~35 MB). Zeroed pads below zA / y2b serve the IIR's
  // negative-row reads; slack after each arena absorbs prefetch overshoot
  // (values unused). Producers only write >= arena start, so pads stay zero.
  double* Scum = (double*)(ws + 0);                   // double[100]
  float*  c1   = (float*)(ws + 1024);                 // float[4704]
  const size_t PADZ = 65536;                          // 655360 B zeros
  const size_t ZA   = PADZ + 655360;                  // 720896: z arena 13.1MB+slack
  const size_t PADY = ZA + 13107200 + 262144;         // 14090240: 131072 B zeros
  const size_t Y2B  = PADY + 131072;                  // 14221312
  const size_t S1B  = Y2B + 2408448 + 65536;          // 16695296
  const size_t S2B  = S1B + 9633792;                  // 26329088
  const size_t S3B  = S2B + 2408448;                  // 28737536
  const size_t S4B  = S3B + 3276800;                  // 32014336
  const size_t S5B  = S4B + 614400;                   // 32628736
  const size_t WA   = S5B + 307200;                   // 32935936
  const size_t WB   = WA + 1920000;                   // 34855936
  const size_t WC   = WB + 180000;                    // 35035936
  float* zA = (float*)(ws + ZA);
  unsigned char* y2b = (unsigned char*)(ws + Y2B);
  unsigned char* s1b = (unsigned char*)(ws + S1B);
  unsigned char* s2b = (unsigned char*)(ws + S2B);
  unsigned char* s3b = (unsigned char*)(ws + S3B);
  unsigned char* s4b = (unsigned char*)(ws + S4B);
  unsigned char* s5b = (unsigned char*)(ws + S5B);
  float* WT1 = (float*)(ws + WA);
  float* WT2 = (float*)(ws + WB);
  float* WT3 = (float*)(ws + WC);

  // IIR coefficients (host math): h[k] = c*k*b^k, truncated at K=100.
  double b = exp(-0.1), c = 0.1 * exp(1.0);
  double A1 = 2.0 * b, A2 = b * b;
  double B1 = c * b;
  double C0 = 100.0 * c * pow(b, 100.0);
  double C1 = 99.0 * c * pow(b, 101.0);
  double sc = (double)1.1f;                  // pool weight, exact fp32 value

  hipMemsetAsync(ws + PADZ, 0, 655360, stream);
  hipMemsetAsync(ws + PADY, 0, 131072, stream);
  k_init<<<1, 64, 0, stream>>>(Scum);
  k_conv1<<<19, 256, 0, stream>>>(x, Wc1, c1);
  k_transpose<<<(1600 * 300 + 255) / 256, 256, 0, stream>>>(Wf1, WT1, 300, 1600);
  k_transpose<<<(300 * 150 + 255) / 256, 256, 0, stream>>>(Wf2, WT2, 150, 300);
  k_transpose<<<(150 * 10 + 255) / 256, 256, 0, stream>>>(Wf3, WT3, 10, 150);
  k_scan1<<<19, 256, 0, stream>>>(c1, Scum, s1b);
  k_pool<<<(1176 * T_BINS) / 256, 256, 0, stream>>>(s1b, y2b);
  k_psp_scan<unsigned char, unsigned char><<<5, 256, 0, stream>>>(
      y2b, s2b, 1176, 1176L, 1L, A1, A2, B1 * sc, C0 * sc, C1 * sc);
  k_conv2<<<T_BINS, 256, 0, stream>>>(s2b, Wc2, zA);
  k_psp_scan<float, unsigned char><<<7, 256, 0, stream>>>(
      zA, s3b, 1600, 1600L, 1L, A1, A2, B1, C0, C1);
  k_dense_sparse<1600, 300, 320><<<T_BINS, 320, 0, stream>>>(s3b, WT1, zA);
  k_psp_scan<float, unsigned char><<<2, 256, 0, stream>>>(
      zA, s4b, 300, 300L, 1L, A1, A2, B1, C0, C1);
  k_dense_sparse<300, 150, 192><<<T_BINS, 192, 0, stream>>>(s4b, WT2, zA);
  k_psp_scan<float, unsigned char><<<1, 256, 0, stream>>>(
      zA, s5b, 150, 150L, 1L, A1, A2, B1, C0, C1);
  k_dense_sparse<150, 10, 64><<<T_BINS, 64, 0, stream>>>(s5b, WT3, zA);
  k_psp_scan<float, float><<<1, 64, 0, stream>>>(
      zA, out, 10, 1L, 2048L, A1, A2, B1, C0, C1);

  (void)in_sizes; (void)n_in; (void)out_size; (void)ws_size;
}

// Round 5
// 363.289 us; speedup vs baseline: 2.3969x; 2.3969x over previous
//
#include <hip/hip_runtime.h>
#include <math.h>

// SLAYER SNN forward, 6 layers, T=2048.
// Double-precision "true value" policy: outputs are binary spikes matching the
// golden fp32 reference; double noise (~1e-13) << reference fp32 noise (~1e-5),
// so any double summation order/reassociation is safe.
//
// PSP (100-tap truncated SRM FIR) folded into an exact 2nd-order IIR:
//   p[t+1] = A1 p[t] - A2 p[t-1] + B1 x[t] - C0 x[t-99] + C1 x[t-100]
// Refractory identity: e1'=a(e1+s), e2'=a(e2+e1+s), a=e^-1; u'=p'-2((e1+e2)+s).
//
// TIME-CHUNKED SPECULATIVE SCAN: T=2048 split into 16 chunks of 128.
// - IIR p-state at chunk warmup start ts is EXACT via 100-tap FIR (p's memory
//   is exactly 101 input steps; rows<0 read zeroed pads).
// - Refractory state speculated (e1,e2)=(0,0) at ts=t0-64 with 64 warmup
//   steps: init error decays e^-1/step; possible warmup spike flips die out
//   ~e^-50 before the output region (margins are >=fp32 noise, observed via
//   4 rounds of bitwise matches). Chunk 0 starts exact at t=0 (no warmup).
// Serial depth per scan: 2048 -> 192 steps, parallel width x16.

#define T_BINS 2048
#define K_SRM  100
#define AEXP   0.36787944117144233   // e^-1
#define CHK    128                   // chunk output length
#define WUP    64                    // refractory warmup length
#define NCHK   (T_BINS / CHK)        // 16

// ---------------- init: Scum prefix + SRM tap table H[0..101] ---------------
__global__ __launch_bounds__(64) void k_init(double* __restrict__ Scum,
                                             double* __restrict__ H) {
  if (threadIdx.x == 0) {
    double acc = 0.0;
    for (int k = 0; k < K_SRM; ++k) {
      double tk = (double)k;
      double h = (tk * 0.1) * exp(1.0 - tk * 0.1);
      H[k] = h; acc += h; Scum[k] = acc;
    }
    H[100] = 0.0; H[101] = 0.0;      // padding for the unified FIR-init loop
  }
}

// ---------------- conv1: [3,32,32] x [6,3,5,5] -> c1[4704] ------------------
__global__ __launch_bounds__(256) void k_conv1(const float* __restrict__ x,
                                               const float* __restrict__ W,
                                               float* __restrict__ c1) {
  int idx = blockIdx.x * blockDim.x + threadIdx.x;
  if (idx >= 4704) return;
  int o = idx / 784, r = idx % 784, i = r / 28, j = r % 28;
  double acc = 0.0;
  for (int ci = 0; ci < 3; ++ci)
    for (int ky = 0; ky < 5; ++ky) {
      const float* xr = x + ci * 1024 + (i + ky) * 32 + j;
      const float* wr = W + ((o * 3 + ci) * 5 + ky) * 5;
#pragma unroll
      for (int kx = 0; kx < 5; ++kx)
        acc += (double)xr[kx] * (double)wr[kx];
    }
  c1[idx] = (float)acc;
}

// ---------------- layer1 chunked scan: p1[t] = c1*Scum[t] -------------------
// 16 chunks x 4704 neurons = 75264 lanes. p exactly known at any t.
__global__ __launch_bounds__(256) void k_scan1_chunk(
    const float* __restrict__ c1, const double* __restrict__ Scum_g,
    unsigned char* __restrict__ s1b) {
  __shared__ double Sc[K_SRM];
  for (int k = threadIdx.x; k < K_SRM; k += 256) Sc[k] = Scum_g[k];
  __syncthreads();
  int idx = blockIdx.x * 256 + threadIdx.x;
  int chunk = idx / 4704, n = idx - chunk * 4704;
  int t0 = chunk * CHK;
  int ts = (chunk == 0) ? 0 : t0 - WUP;
  double w = (double)c1[n];
  double e1 = 0.0, e2 = 0.0;
  double u = w * Sc[ts < (K_SRM - 1) ? ts : (K_SRM - 1)];  // e-state speculated 0
  unsigned char* outp = s1b + n;
  for (int t = ts; t < t0; ++t) {       // warmup, no store
    double s = (u >= 1.0) ? 1.0 : 0.0;
    int si = t + 1 < (K_SRM - 1) ? t + 1 : (K_SRM - 1);
    u = w * Sc[si] - 2.0 * ((e1 + e2) + s);
    double t1 = e1 + s;
    e2 = AEXP * (e2 + t1); e1 = AEXP * t1;
  }
#pragma unroll 8
  for (int t = t0; t < t0 + CHK; ++t) { // output
    double s = (u >= 1.0) ? 1.0 : 0.0;
    outp[(size_t)t * 4704] = (unsigned char)s;
    int si = t + 1 < (K_SRM - 1) ? t + 1 : (K_SRM - 1);
    u = w * Sc[si] - 2.0 * ((e1 + e2) + s);
    double t1 = e1 + s;
    e2 = AEXP * (e2 + t1); e1 = AEXP * t1;
  }
}

// ---------------- pool: 2x2 spike count -> y2b[t][1176] bytes ---------------
__global__ __launch_bounds__(256) void k_pool(const unsigned char* __restrict__ s1b,
                                              unsigned char* __restrict__ y2b) {
  int idx = blockIdx.x * blockDim.x + threadIdx.x;
  if (idx >= 1176 * T_BINS) return;
  int t = idx / 1176, n2 = idx - t * 1176;
  int c = n2 / 196, r = n2 % 196, i = r / 14, j = r % 14;
  const unsigned char* b = s1b + (size_t)t * 4704 + c * 784 + (2 * i) * 28 + 2 * j;
  y2b[idx] = (unsigned char)((int)b[0] + (int)b[1] + (int)b[28] + (int)b[29]);
}

// ---------------- chunked fused PSP(IIR) + spike scan -----------------------
// lanes = chunk*N + n. IIR state at ts via exact FIR; refractory speculated.
// Rows < 0 hit zeroed pads; prefetch overshoot lands in in-bounds slack
// (or pre-pad regions for the FIR's last group) -- loaded but never used.
template <typename Tin, typename Tout>
__global__ __launch_bounds__(256) void k_psp_scan_chunk(
    const Tin* __restrict__ z, Tout* __restrict__ sout, int N,
    long strideT, long strideN, const double* __restrict__ H_g,
    double A1, double A2, double B1, double C0, double C1, double xscale) {
  __shared__ double Hs[102];
  for (int k = threadIdx.x; k < 102; k += 256) Hs[k] = H_g[k];
  __syncthreads();
  int idx = blockIdx.x * blockDim.x + threadIdx.x;
  if (idx >= NCHK * N) return;
  int chunk = idx / N, n = idx - chunk * N;
  int t0 = chunk * CHK;
  int ts = (chunk == 0) ? 0 : t0 - WUP;
  const Tin* zn = z + n;

  // --- exact IIR init: accA=p[ts], accB=p[ts-1] (100-tap FIR, 10-deep pipe)
  double accA = 0.0, accB = 0.0;
  float fA[10], fB[10];
#define LOADF(BUF, J0)                                               \
  { _Pragma("unroll")                                                \
    for (int q_ = 0; q_ < 10; ++q_)                                  \
      BUF[q_] = (float)zn[(long)(ts - 1 - ((J0) + q_)) * (long)N]; }
#define FMA10(BUF, J0)                                               \
  { _Pragma("unroll")                                                \
    for (int q_ = 0; q_ < 10; ++q_) {                                \
      double v_ = (double)BUF[q_];                                   \
      accA += Hs[(J0) + q_ + 1] * v_;                                \
      accB += Hs[(J0) + q_] * v_;                                    \
    } }
  LOADF(fA, 0)
  for (int q = 0; q < 100; q += 20) {
    LOADF(fB, q + 10)
    FMA10(fA, q)
    LOADF(fA, q + 20)                  // q=80: overshoot, in-bounds, unused
    FMA10(fB, q + 10)
  }
#undef LOADF
#undef FMA10
  double pp1 = accA * xscale;          // p[ts]
  double pp2 = accB * xscale;          // p[ts-1]
  double xm100 = (double)(float)zn[(long)(ts - 100) * (long)N];
  double u = pp1, e1 = 0.0, e2 = 0.0;  // refractory speculated zero

  // --- scan: groups of 8, double-buffered prefetch of cur + lag streams
  float cA[8], cB[8], lA[8], lB[8];
  size_t oa = (size_t)n * (size_t)strideN + (size_t)t0 * (size_t)strideT;
  int nwg = (t0 - ts) >> 3;            // 0 or 8 warmup groups
  int ngrp = nwg + CHK / 8;            // 16 or 24 (even)
#define PREF8(CBUF, LBUF, TB)                                        \
  { long tb_ = (long)(TB);                                           \
    _Pragma("unroll")                                                \
    for (int j_ = 0; j_ < 8; ++j_) {                                 \
      CBUF[j_] = (float)zn[(tb_ + j_) * (long)N];                    \
      LBUF[j_] = (float)zn[(tb_ + j_ - 99) * (long)N];               \
    } }
#define PROC8(CBUF, LBUF, DOSTORE)                                   \
  { _Pragma("unroll")                                                \
    for (int j_ = 0; j_ < 8; ++j_) {                                 \
      double s = (u >= 1.0) ? 1.0 : 0.0;                             \
      if (DOSTORE) { sout[oa] = (Tout)s; oa += (size_t)strideT; }    \
      double xt = (double)CBUF[j_], x99 = (double)LBUF[j_];          \
      double pn = A1 * pp1 - A2 * pp2 + B1 * xt - C0 * x99           \
                  + C1 * xm100;                                      \
      xm100 = x99;                                                   \
      u = pn - 2.0 * ((e1 + e2) + s);                                \
      double t1 = e1 + s;                                            \
      e2 = AEXP * (e2 + t1); e1 = AEXP * t1;                         \
      pp2 = pp1; pp1 = pn;                                           \
    } }
  PREF8(cA, lA, ts)
  for (int g = 0; g < ngrp; g += 2) {
    PREF8(cB, lB, ts + (g + 1) * 8)
    PROC8(cA, lA, g >= nwg)
    PREF8(cA, lA, ts + (g + 2) * 8)    // last iter overshoots into slack
    PROC8(cB, lB, g + 1 >= nwg)
  }
#undef PREF8
#undef PROC8
}

// ---------------- conv2: per-t [6,14,14] x [16,6,5,5] -> z3[t][1600] --------
__global__ __launch_bounds__(256) void k_conv2(const unsigned char* __restrict__ s2b,
                                               const float* __restrict__ W,
                                               float* __restrict__ z3) {
  __shared__ float ls[1176];
  __shared__ float lw[2400];
  int t = blockIdx.x;
  for (int i = threadIdx.x; i < 1176; i += 256)
    ls[i] = (float)s2b[(size_t)t * 1176 + i];
  for (int i = threadIdx.x; i < 2400; i += 256) lw[i] = W[i];
  __syncthreads();
  for (int rr = threadIdx.x; rr < 1600; rr += 256) {
    int o = rr / 100, ij = rr % 100, i = ij / 10, j = ij % 10;
    double acc = 0.0;
    for (int ci = 0; ci < 6; ++ci)
      for (int ky = 0; ky < 5; ++ky) {
        int sb = ci * 196 + (i + ky) * 14 + j;
        int wb = ((o * 6 + ci) * 5 + ky) * 5;
#pragma unroll
        for (int kx = 0; kx < 5; ++kx)
          acc += (double)ls[sb + kx] * (double)lw[wb + kx];
      }
    z3[(size_t)t * 1600 + rr] = (float)acc;
  }
}

// ---------------- weight transpose: WT[c][o] = W[o][c] ----------------------
__global__ __launch_bounds__(256) void k_transpose(const float* __restrict__ W,
                                                   float* __restrict__ WT,
                                                   int Nout, int Nin) {
  int idx = blockIdx.x * blockDim.x + threadIdx.x;
  if (idx >= Nout * Nin) return;
  int c = idx / Nout, o = idx - c * Nout;   // write-coalesced
  WT[idx] = W[o * Nin + c];
}

// ---------------- sparse dense: z[t][o] = sum_{c active} WT[c][o] -----------
// One block per t. Order-preserving compaction (ascending c), then
// 4-accumulator double sum; list read via int4 LDS broadcast.
template <int NIN, int NOUT, int BLK>
__global__ __launch_bounds__(BLK) void k_dense_sparse(
    const unsigned char* __restrict__ s, const float* __restrict__ WT,
    float* __restrict__ z) {
  constexpr int NCH = (NIN + BLK - 1) / BLK;
  constexpr int NW = BLK / 64;
  __shared__ __align__(16) int list[NIN];
  __shared__ int wcnt[NCH][NW];
  int t = blockIdx.x;
  const unsigned char* srow = s + (size_t)t * NIN;
  int tid = threadIdx.x, lane = tid & 63, wv = tid >> 6;
  unsigned long long msave[NCH];
  bool asave[NCH];
#pragma unroll
  for (int ci = 0; ci < NCH; ++ci) {
    int c = ci * BLK + tid;
    bool a = (c < NIN) && (srow[c] != 0);
    unsigned long long m = __ballot(a);
    msave[ci] = m; asave[ci] = a;
    if (lane == 0) wcnt[ci][wv] = __popcll(m);
  }
  __syncthreads();
  int nact = 0;
#pragma unroll
  for (int ci = 0; ci < NCH; ++ci) {
    int off = nact;
    for (int w = 0; w < wv; ++w) off += wcnt[ci][w];
    if (asave[ci])
      list[off + __popcll(msave[ci] & ((1ULL << lane) - 1))] = ci * BLK + tid;
    for (int w = 0; w < NW; ++w) nact += wcnt[ci][w];
  }
  __syncthreads();
  if (tid >= NOUT) return;
  const float* col = WT + tid;
  double a0 = 0.0, a1 = 0.0, a2 = 0.0, a3 = 0.0;
  int k = 0, nact4 = nact & ~3;
  for (; k < nact4; k += 4) {
    int4 l4 = *(const int4*)&list[k];
    a0 += (double)col[(size_t)l4.x * NOUT];
    a1 += (double)col[(size_t)l4.y * NOUT];
    a2 += (double)col[(size_t)l4.z * NOUT];
    a3 += (double)col[(size_t)l4.w * NOUT];
  }
  for (; k < nact; ++k) a0 += (double)col[(size_t)list[k] * NOUT];
  z[(size_t)t * NOUT + tid] = (float)((a0 + a1) + (a2 + a3));
}

// ---------------- launch ----------------------------------------------------
extern "C" void kernel_launch(void* const* d_in, const int* in_sizes, int n_in,
                              void* d_out, int out_size, void* d_ws, size_t ws_size,
                              hipStream_t stream) {
  const float* x   = (const float*)d_in[0];
  const float* Wc1 = (const float*)d_in[1];
  const float* Wc2 = (const float*)d_in[2];
  const float* Wf1 = (const float*)d_in[3];
  const float* Wf2 = (const float*)d_in[4];
  const float* Wf3 = (const float*)d_in[5];
  float* out = (float*)d_out;
  char* ws = (char*)d_ws;

  // Workspace layout (~35 MB). Zeroed pads below zA / y2b serve the FIR/IIR's
  // negative-row reads (>=100 rows of max-N); slack after arenas absorbs
  // prefetch overshoot (unused values). Producers write only rows >= 0.
  double* Scum = (double*)(ws + 0);                   // double[100]
  double* Htab = (double*)(ws + 2048);                // double[102]
  float*  c1   = (float*)(ws + 4096);                 // float[4704]
  const size_t PADZ = 65536;                          // 655360 B zeros
  const size_t ZA   = PADZ + 655360;                  // z arena 13.1MB + slack
  const size_t PADY = ZA + 13107200 + 262144;         // 131072 B zeros
  const size_t Y2B  = PADY + 131072;
  const size_t S1B  = Y2B + 2408448 + 65536;
  const size_t S2B  = S1B + 9633792;
  const size_t S3B  = S2B + 2408448;
  const size_t S4B  = S3B + 3276800;
  const size_t S5B  = S4B + 614400;
  const size_t WA   = S5B + 307200;
  const size_t WB   = WA + 1920000;
  const size_t WC   = WB + 180000;
  float* zA = (float*)(ws + ZA);
  unsigned char* y2b = (unsigned char*)(ws + Y2B);
  unsigned char* s1b = (unsigned char*)(ws + S1B);
  unsigned char* s2b = (unsigned char*)(ws + S2B);
  unsigned char* s3b = (unsigned char*)(ws + S3B);
  unsigned char* s4b = (unsigned char*)(ws + S4B);
  unsigned char* s5b = (unsigned char*)(ws + S5B);
  float* WT1 = (float*)(ws + WA);
  float* WT2 = (float*)(ws + WB);
  float* WT3 = (float*)(ws + WC);

  // IIR coefficients (host, double): h[k] = c*k*b^k, truncated at K=100.
  double b = exp(-0.1), c = 0.1 * exp(1.0);
  double A1 = 2.0 * b, A2 = b * b;
  double B1 = c * b;
  double C0 = 100.0 * c * pow(b, 100.0);
  double C1 = 99.0 * c * pow(b, 101.0);
  double sc = (double)1.1f;                  // pool weight, exact fp32 value

  hipMemsetAsync(ws + PADZ, 0, 655360, stream);
  hipMemsetAsync(ws + PADY, 0, 131072, stream);
  k_init<<<1, 64, 0, stream>>>(Scum, Htab);
  k_conv1<<<19, 256, 0, stream>>>(x, Wc1, c1);
  k_transpose<<<(1600 * 300 + 255) / 256, 256, 0, stream>>>(Wf1, WT1, 300, 1600);
  k_transpose<<<(300 * 150 + 255) / 256, 256, 0, stream>>>(Wf2, WT2, 150, 300);
  k_transpose<<<(150 * 10 + 255) / 256, 256, 0, stream>>>(Wf3, WT3, 10, 150);
  k_scan1_chunk<<<NCHK * 4704 / 256, 256, 0, stream>>>(c1, Scum, s1b);
  k_pool<<<(1176 * T_BINS) / 256, 256, 0, stream>>>(s1b, y2b);
  k_psp_scan_chunk<unsigned char, unsigned char>
      <<<(NCHK * 1176 + 255) / 256, 256, 0, stream>>>(
      y2b, s2b, 1176, 1176L, 1L, Htab, A1, A2, B1 * sc, C0 * sc, C1 * sc, sc);
  k_conv2<<<T_BINS, 256, 0, stream>>>(s2b, Wc2, zA);
  k_psp_scan_chunk<float, unsigned char>
      <<<(NCHK * 1600 + 255) / 256, 256, 0, stream>>>(
      zA, s3b, 1600, 1600L, 1L, Htab, A1, A2, B1, C0, C1, 1.0);
  k_dense_sparse<1600, 300, 320><<<T_BINS, 320, 0, stream>>>(s3b, WT1, zA);
  k_psp_scan_chunk<float, unsigned char>
      <<<(NCHK * 300 + 255) / 256, 256, 0, stream>>>(
      zA, s4b, 300, 300L, 1L, Htab, A1, A2, B1, C0, C1, 1.0);
  k_dense_sparse<300, 150, 192><<<T_BINS, 192, 0, stream>>>(s4b, WT2, zA);
  k_psp_scan_chunk<float, unsigned char>
      <<<(NCHK * 150 + 255) / 256, 256, 0, stream>>>(
      zA, s5b, 150, 150L, 1L, Htab, A1, A2, B1, C0, C1, 1.0);
  k_dense_sparse<150, 10, 64><<<T_BINS, 64, 0, stream>>>(s5b, WT3, zA);
  k_psp_scan_chunk<float, float><<<1, 192, 0, stream>>>(
      zA, out, 10, 1L, 2048L, Htab, A1, A2, B1, C0, C1, 1.0);

  (void)in_sizes; (void)n_in; (void)out_size; (void)ws_size;
}